// Round 8
// baseline (170.742 us; speedup 1.0000x reference)
//
#include <hip/hip_runtime.h>
#include <hip/hip_bf16.h>

#define CIN  64
#define COUT 64
#define HH   64
#define WW   64
#define HW   4096
#define OFFC 18
#define KK2  9
#define II   576            // CIN * KK2
#define NP   16             // pixels per block in main kernel
#define SMPW (II + 8)       // 584 bf16 -> row stride 1168 B (odd multiple of 16B)
#define NKC  (II / 32)      // 18 k-chunks for 16x16x32 MFMA
#define IMGB (HW * CIN * 2) // bytes per bf16 image = 524288

typedef __attribute__((ext_vector_type(8))) short  short8;   // 8 x bf16 (A/B frag)
typedef __attribute__((ext_vector_type(4))) float  f32x4;    // C/D frag

__device__ __forceinline__ float u2f(unsigned int u) {
    union { unsigned int i; float f; } v; v.i = u; return v.f;
}
__device__ __forceinline__ short8 as_short8(uint4 u) {
    union { uint4 a; short8 b; } v; v.a = u; return v.b;
}
__device__ __forceinline__ unsigned short f2bf_bits(float f) {
    union { __hip_bfloat16 b; unsigned short s; } cv;
    cv.b = __float2bfloat16(f);
    return cv.s;
}
__device__ __forceinline__ float2 bfpair(unsigned int u) {   // (lo bf16, hi bf16) -> float2
    float2 r; r.x = u2f(u << 16); r.y = u2f(u & 0xffff0000u); return r;
}

// ---------- K1: transpose x (NCHW f32 -> NHWC bf16) + pack both weight tensors ----------
// blocks 0..2047: transpose one (b,h) row. blocks 2048..2263: weight packing.
__global__ __launch_bounds__(256) void prep(const float* __restrict__ x,
                                            const float* __restrict__ wc,
                                            const float* __restrict__ w,
                                            __hip_bfloat16* __restrict__ xT,
                                            __hip_bfloat16* __restrict__ wmp,
                                            __hip_bfloat16* __restrict__ bop) {
    const int t = threadIdx.x;
    if (blockIdx.x < 2048) {
        __shared__ float tile[64][68];                // 68: 16B-aligned float4 rows, 2-way banks
        const int b = blockIdx.x >> 6, h = blockIdx.x & 63;
        {
            const int w4 = t & 15, cg = t >> 4;       // 16 float4 chunks x 16 c-groups
            #pragma unroll
            for (int i = 0; i < 4; ++i) {
                const int c = cg + i * 16;
                const float4 v = *(const float4*)&x[((b * 64 + c) * 64 + h) * 64 + w4 * 4];
                *(float4*)&tile[c][w4 * 4] = v;       // ds_write_b128
            }
        }
        __syncthreads();
        {
            const int ww = t & 63, c0 = (t >> 6) * 16;
            unsigned int pk[8];
            #pragma unroll
            for (int ci = 0; ci < 8; ++ci) {
                const unsigned int lo = f2bf_bits(tile[c0 + 2 * ci][ww]);
                const unsigned int hi = f2bf_bits(tile[c0 + 2 * ci + 1][ww]);
                pk[ci] = lo | (hi << 16);
            }
            char* dst = (char*)xT + (size_t)(((b * 64 + h) * 64 + ww) * 64 + c0) * 2;
            uint4 v0, v1;
            v0.x = pk[0]; v0.y = pk[1]; v0.z = pk[2]; v0.w = pk[3];
            v1.x = pk[4]; v1.y = pk[5]; v1.z = pk[6]; v1.w = pk[7];
            *(uint4*)dst = v0;                        // 32 contiguous B per thread
            *(uint4*)(dst + 16) = v1;
        }
    } else {
        // smp k-ordering: s = kk*64 + c; packs apply matching permutation
        const int idx = (blockIdx.x - 2048) * 256 + t;    // 0..55295
        if (idx < 4 * NKC * 64 * 8) {
            const int j    = idx & 7;
            const int lane = (idx >> 3) & 63;
            const int kc   = (idx >> 9) % NKC;
            const int nt   = idx / (NKC * 512);
            const int o  = nt * 16 + (lane & 15);
            const int ks = kc * 32 + (lane >> 4) * 8 + j;
            const int c  = ks & 63, kk = ks >> 6;
            wmp[idx] = __float2bfloat16(wc[(o * CIN + c) * KK2 + kk]);
        } else {
            const int i2 = idx - 4 * NKC * 64 * 8;        // 0..18431
            const int j    = i2 & 7;
            const int lane = (i2 >> 3) & 63;
            const int kc   = (i2 >> 9) % NKC;
            const int nt   = i2 / (NKC * 512);
            const int ch = nt * 16 + (lane & 15);
            const int ks = kc * 32 + (lane >> 4) * 8 + j;
            const int c  = ks & 63, kk = ks >> 6;
            bop[i2] = (ch < OFFC) ? __float2bfloat16(w[(ch * CIN + c) * KK2 + kk])
                                  : __float2bfloat16(0.f);
        }
    }
}

// ---------- K2: fused offset conv (MFMA, A direct-from-global) + fold + gather + main GEMM ----------
__global__ __launch_bounds__(256, 7) void deform_fused(const __hip_bfloat16* __restrict__ xT,
                                                       const __hip_bfloat16* __restrict__ bop,
                                                       const __hip_bfloat16* __restrict__ wmp,
                                                       const float* __restrict__ boff,
                                                       const float* __restrict__ bconv,
                                                       float* __restrict__ out) {
    __shared__ __hip_bfloat16 smp[NP][SMPW];          // 18688 B; aliased: pacc early, outb late
    __shared__ uint4 metal[NP * KK2];                 // 2304 B

    const int t = threadIdx.x;
    const int wave = t >> 6, lane = t & 63;
    const int sp0g = blockIdx.x * NP;
    const int b = sp0g >> 12, sp0 = sp0g & 4095;
    const int ho = sp0 >> 6, wo0 = sp0 & 63;          // NP=16 divides 64 -> row-uniform block
    const char* xbB = (const char*)xT + (size_t)b * IMGB;

    // ---- phase 1: offset conv partials; 18 (tap,half) units round-robin over waves (5/5/4/4) ----
    f32x4 acc0 = {0.f, 0.f, 0.f, 0.f};               // ch 0..15
    f32x4 acc1 = {0.f, 0.f, 0.f, 0.f};               // ch 16,17
    {
        const int m = lane & 15, quad = lane >> 4;
        const short8* bp = (const short8*)bop;
        for (int u = wave; u < 2 * KK2; u += 4) {
            const int kk = u >> 1, h = u & 1;         // k-chunk kc = 2*kk+h covers ch 32h..32h+31
            const int ki = kk / 3, kj = kk - ki * 3;
            const int y = ho - 1 + ki;                // wave-uniform
            if ((unsigned)y < HH) {
                const int col = wo0 + m + kj - 1;
                const int ccl = min(max(col, 0), WW - 1);
                const bool ok = (unsigned)col < WW;
                uint4 v = *(const uint4*)(xbB + (y * 64 + ccl) * 128 + quad * 16 + h * 64);
                if (!ok) { v.x = 0u; v.y = 0u; v.z = 0u; v.w = 0u; }
                const int kc = 2 * kk + h;
                acc0 = __builtin_amdgcn_mfma_f32_16x16x32_bf16(as_short8(v), bp[kc * 64 + lane], acc0, 0, 0, 0);
                acc1 = __builtin_amdgcn_mfma_f32_16x16x32_bf16(as_short8(v), bp[(NKC + kc) * 64 + lane], acc1, 0, 0, 0);
            }
        }
        // store wave partials: pacc[4][16 px][20 ch] aliases smp
        float* pacc = (float*)&smp[0][0];
        const int n = lane & 15;
        #pragma unroll
        for (int r = 0; r < 4; ++r) {
            const int p = quad * 4 + r;               // D: col=ch, row=quad*4+r (pixel)
            pacc[(wave * 16 + p) * 20 + n] = acc0[r];
            if (n < 2) pacc[(wave * 16 + p) * 20 + 16 + n] = acc1[r];
        }
    }
    __syncthreads();

    // ---- phase 2: reduce partials (float2) + bias + fold -> metal (144 taps, 1 thread each) ----
    if (t < NP * KK2) {
        const float* pacc = (const float*)&smp[0][0];
        const int p = t / KK2, kk = t - p * KK2;
        const float2 bb = *(const float2*)&boff[2 * kk];
        float2 d = bb;
        #pragma unroll
        for (int wv = 0; wv < 4; ++wv) {
            const float2 pp = *(const float2*)&pacc[(wv * 16 + p) * 20 + 2 * kk];
            d.x += pp.x; d.y += pp.y;
        }
        const float dy = d.x, dx = d.y;
        const int wo = wo0 + p;
        const int ki = kk / 3, kj = kk - ki * 3;
        const float py = (float)(ho - 1 + ki) + dy;
        const float px = (float)(wo - 1 + kj) + dx;
        const float y0f = floorf(py), x0f = floorf(px);
        const int y0 = (int)y0f, x0 = (int)x0f;
        const float wy1 = py - y0f, wx1 = px - x0f;
        const float wy0 = 1.f - wy1, wx0 = 1.f - wx1;
        const int yb = min(max(y0, 0), HH - 2);
        const int zb = min(max(x0, 0), WW - 2);
        const float vy0 = ((unsigned)y0 < HH) ? wy0 : 0.f;
        const float vy1 = ((unsigned)(y0 + 1) < HH) ? wy1 : 0.f;
        const float vx0 = ((unsigned)x0 < WW) ? wx0 : 0.f;
        const float vx1 = ((unsigned)(x0 + 1) < WW) ? wx1 : 0.f;
        const float t0 = (y0 == yb ? vy0 : 0.f) + (y0 + 1 == yb ? vy1 : 0.f);
        const float t1 = (y0 == yb + 1 ? vy0 : 0.f) + (y0 + 1 == yb + 1 ? vy1 : 0.f);
        const float u0 = (x0 == zb ? vx0 : 0.f) + (x0 + 1 == zb ? vx1 : 0.f);
        const float u1 = (x0 == zb + 1 ? vx0 : 0.f) + (x0 + 1 == zb + 1 ? vx1 : 0.f);
        union { unsigned int u; _Float16 h[2]; } c0, c1;
        c0.h[0] = (_Float16)(t0 * u0); c0.h[1] = (_Float16)(t1 * u0);  // w00, w10 (col zb)
        c1.h[0] = (_Float16)(t0 * u1); c1.h[1] = (_Float16)(t1 * u1);  // w01, w11 (col zb+1)
        uint4 mt;
        mt.x = (unsigned int)((yb * 64 + zb) * 128);  // byte offset into bf16 image
        mt.y = c0.u; mt.z = c1.u; mt.w = 0u;
        metal[t] = mt;
    }
    __syncthreads();                                  // pacc reads done; metal ready

    // ---- phase 3: gather; 36 instances (4 px x 9 taps)/wave, 4/pass, 4 ch/lane dwordx2 ----
    {
        const int li4 = lane & 15;                    // ch group: ch 4*li4 .. +3
        const int tg  = lane >> 4;                    // instance slot in pass
        const char* xli = xbB + li4 * 8;
        const int p0 = wave * 4;
        #pragma unroll
        for (int s = 0; s < 9; ++s) {
            const int e  = s * 4 + tg;                // 0..35, exact cover, no idle
            const int pl = e / 9;
            const int kk = e - pl * 9;
            const uint4 mt = metal[p0 * KK2 + e];     // 4-addr broadcast ds_read_b128
            const char* base = xli + (int)mt.x;
            const uint2 r00 = *(const uint2*)(base);          // row yb,   col zb
            const uint2 r01 = *(const uint2*)(base + 128);    // row yb,   col zb+1
            const uint2 r10 = *(const uint2*)(base + 8192);   // row yb+1, col zb
            const uint2 r11 = *(const uint2*)(base + 8320);   // row yb+1, col zb+1
            union { unsigned int u; _Float16 h[2]; } c0, c1;
            c0.u = mt.y; c1.u = mt.z;
            const float w00 = (float)c0.h[0], w10 = (float)c0.h[1];
            const float w01 = (float)c1.h[0], w11 = (float)c1.h[1];
            float2 v0, v1;
            {
                const float2 a00 = bfpair(r00.x), a01 = bfpair(r01.x);
                const float2 a10 = bfpair(r10.x), a11 = bfpair(r11.x);
                v0.x = w00 * a00.x + w01 * a01.x + w10 * a10.x + w11 * a11.x;
                v0.y = w00 * a00.y + w01 * a01.y + w10 * a10.y + w11 * a11.y;
            }
            {
                const float2 a00 = bfpair(r00.y), a01 = bfpair(r01.y);
                const float2 a10 = bfpair(r10.y), a11 = bfpair(r11.y);
                v1.x = w00 * a00.x + w01 * a01.x + w10 * a10.x + w11 * a11.x;
                v1.y = w00 * a00.y + w01 * a01.y + w10 * a10.y + w11 * a11.y;
            }
            union { struct { __hip_bfloat162 a, b; } s2; uint2 u; } st;
            st.s2.a = __float22bfloat162_rn(v0);      // ch 4li4, 4li4+1
            st.s2.b = __float22bfloat162_rn(v1);      // ch 4li4+2, +3
            *(uint2*)((char*)&smp[p0 + pl][0] + kk * 128 + li4 * 8) = st.u;  // ds_write_b64
        }
    }
    __syncthreads();

    // ---- phase 4: main GEMM 16 x 576 @ 576 x 64; wave = 16-col N-tile ----
    f32x4 acc = {0.f, 0.f, 0.f, 0.f};
    {
        const char* abase = (const char*)&smp[lane & 15][0] + (lane >> 4) * 16;
        const short8* wp = (const short8*)wmp + wave * NKC * 64 + lane;
        #pragma unroll
        for (int kc = 0; kc < NKC; ++kc) {
            const short8 a  = *(const short8*)(abase + kc * 64);   // ds_read_b128
            const short8 bw = wp[kc * 64];                         // global, L1/L2-hot
            acc = __builtin_amdgcn_mfma_f32_16x16x32_bf16(a, bw, acc, 0, 0, 0);
        }
    }
    __syncthreads();                                  // smp reads done; alias as outb

    // ---- phase 5: epilogue via LDS for coalesced stores ----
    {
        float* outb = (float*)&smp[0][0];             // [64][17] floats = 4352 B
        const int o = wave * 16 + (lane & 15);
        const float bias = bconv[o];
        const int pr = (lane >> 4) * 4;
        #pragma unroll
        for (int r = 0; r < 4; ++r)
            outb[o * 17 + pr + r] = acc[r] + bias;
    }
    __syncthreads();
    {
        const float* outb = (const float*)&smp[0][0];
        const int oo = t >> 2, pxb = (t & 3) * 4;
        const float* lb = outb + oo * 17 + pxb;
        float4 v;
        v.x = lb[0]; v.y = lb[1]; v.z = lb[2]; v.w = lb[3];
        *(float4*)(out + ((size_t)(b * COUT + oo)) * HW + sp0 + pxb) = v;
    }
}

extern "C" void kernel_launch(void* const* d_in, const int* in_sizes, int n_in,
                              void* d_out, int out_size, void* d_ws, size_t ws_size,
                              hipStream_t stream) {
    const float* x      = (const float*)d_in[0];
    const float* w_off  = (const float*)d_in[1];
    const float* b_off  = (const float*)d_in[2];
    const float* w_conv = (const float*)d_in[3];
    const float* b_conv = (const float*)d_in[4];
    float* out = (float*)d_out;

    // ws: xT bf16 16.78MB | wmp 73728B | bop 36864B
    __hip_bfloat16* xT  = (__hip_bfloat16*)d_ws;
    __hip_bfloat16* wmp = xT + (size_t)32 * HW * CIN;
    __hip_bfloat16* bop = wmp + 4 * NKC * 64 * 8;

    hipLaunchKernelGGL(prep, dim3(2048 + 216), dim3(256), 0, stream,
                       x, w_conv, w_off, xT, wmp, bop);
    hipLaunchKernelGGL(deform_fused, dim3(32 * HW / NP), dim3(256), 0, stream,
                       xT, bop, wmp, b_off, b_conv, out);
}

// Round 9
// 159.118 us; speedup vs baseline: 1.0731x; 1.0731x over previous
//
#include <hip/hip_runtime.h>
#include <hip/hip_bf16.h>

#define CIN  64
#define COUT 64
#define HH   64
#define WW   64
#define HW   4096
#define OFFC 18
#define KK2  9
#define II   576            // CIN * KK2
#define NP   16             // pixels per block in main kernel
#define SMPW (II + 8)       // 584 bf16 -> row stride 1168 B (odd multiple of 16B)
#define NKC  (II / 32)      // 18 k-chunks for 16x16x32 MFMA
#define IMGB (HW * CIN * 2) // bytes per bf16 image = 524288

typedef __attribute__((ext_vector_type(8))) short  short8;   // 8 x bf16 (A/B frag)
typedef __attribute__((ext_vector_type(4))) float  f32x4;    // C/D frag

__device__ __forceinline__ float u2f(unsigned int u) {
    union { unsigned int i; float f; } v; v.i = u; return v.f;
}
__device__ __forceinline__ short8 as_short8(uint4 u) {
    union { uint4 a; short8 b; } v; v.a = u; return v.b;
}
__device__ __forceinline__ unsigned short f2bf_bits(float f) {
    union { __hip_bfloat16 b; unsigned short s; } cv;
    cv.b = __float2bfloat16(f);
    return cv.s;
}

// ---------- K1: transpose x (NCHW f32 -> NHWC bf16) + pack both weight tensors ----------
// blocks 0..2047: transpose one (b,h) row. blocks 2048..2263: weight packing.
__global__ __launch_bounds__(256) void prep(const float* __restrict__ x,
                                            const float* __restrict__ wc,
                                            const float* __restrict__ w,
                                            __hip_bfloat16* __restrict__ xT,
                                            __hip_bfloat16* __restrict__ wmp,
                                            __hip_bfloat16* __restrict__ bop) {
    const int t = threadIdx.x;
    if (blockIdx.x < 2048) {
        __shared__ float tile[64][68];                // 68: 16B-aligned float4 rows, 2-way banks
        const int b = blockIdx.x >> 6, h = blockIdx.x & 63;
        {
            const int w4 = t & 15, cg = t >> 4;       // 16 float4 chunks x 16 c-groups
            #pragma unroll
            for (int i = 0; i < 4; ++i) {
                const int c = cg + i * 16;
                const float4 v = *(const float4*)&x[((b * 64 + c) * 64 + h) * 64 + w4 * 4];
                *(float4*)&tile[c][w4 * 4] = v;       // ds_write_b128
            }
        }
        __syncthreads();
        {
            const int ww = t & 63, c0 = (t >> 6) * 16;
            unsigned int pk[8];
            #pragma unroll
            for (int ci = 0; ci < 8; ++ci) {
                const unsigned int lo = f2bf_bits(tile[c0 + 2 * ci][ww]);
                const unsigned int hi = f2bf_bits(tile[c0 + 2 * ci + 1][ww]);
                pk[ci] = lo | (hi << 16);
            }
            char* dst = (char*)xT + (size_t)(((b * 64 + h) * 64 + ww) * 64 + c0) * 2;
            uint4 v0, v1;
            v0.x = pk[0]; v0.y = pk[1]; v0.z = pk[2]; v0.w = pk[3];
            v1.x = pk[4]; v1.y = pk[5]; v1.z = pk[6]; v1.w = pk[7];
            *(uint4*)dst = v0;                        // 32 contiguous B per thread
            *(uint4*)(dst + 16) = v1;
        }
    } else {
        // smp k-ordering: s = kk*64 + c; packs apply matching permutation
        const int idx = (blockIdx.x - 2048) * 256 + t;    // 0..55295
        if (idx < 4 * NKC * 64 * 8) {
            const int j    = idx & 7;
            const int lane = (idx >> 3) & 63;
            const int kc   = (idx >> 9) % NKC;
            const int nt   = idx / (NKC * 512);
            const int o  = nt * 16 + (lane & 15);
            const int ks = kc * 32 + (lane >> 4) * 8 + j;
            const int c  = ks & 63, kk = ks >> 6;
            wmp[idx] = __float2bfloat16(wc[(o * CIN + c) * KK2 + kk]);
        } else {
            const int i2 = idx - 4 * NKC * 64 * 8;        // 0..18431
            const int j    = i2 & 7;
            const int lane = (i2 >> 3) & 63;
            const int kc   = (i2 >> 9) % NKC;
            const int nt   = i2 / (NKC * 512);
            const int ch = nt * 16 + (lane & 15);
            const int ks = kc * 32 + (lane >> 4) * 8 + j;
            const int c  = ks & 63, kk = ks >> 6;
            bop[i2] = (ch < OFFC) ? __float2bfloat16(w[(ch * CIN + c) * KK2 + kk])
                                  : __float2bfloat16(0.f);
        }
    }
}

// ---------- K2: fused offset conv (MFMA, A direct-from-global) + fold + gather + main GEMM ----------
__global__ __launch_bounds__(256, 7) void deform_fused(const __hip_bfloat16* __restrict__ xT,
                                                       const __hip_bfloat16* __restrict__ bop,
                                                       const __hip_bfloat16* __restrict__ wmp,
                                                       const float* __restrict__ boff,
                                                       const float* __restrict__ bconv,
                                                       float* __restrict__ out) {
    __shared__ __hip_bfloat16 smp[NP][SMPW];          // 18688 B; aliased: pacc early, outb late
    __shared__ uint4 metal[NP * KK2];                 // 2304 B

    const int t = threadIdx.x;
    const int wave = t >> 6, lane = t & 63;
    const int sp0g = blockIdx.x * NP;
    const int b = sp0g >> 12, sp0 = sp0g & 4095;
    const int ho = sp0 >> 6, wo0 = sp0 & 63;          // NP=16 divides 64 -> row-uniform block
    const char* xbB = (const char*)xT + (size_t)b * IMGB;

    // ---- phase 1: offset conv partials; 18 (tap,half) units round-robin over waves (5/5/4/4) ----
    f32x4 acc0 = {0.f, 0.f, 0.f, 0.f};               // ch 0..15
    f32x4 acc1 = {0.f, 0.f, 0.f, 0.f};               // ch 16,17
    {
        const int m = lane & 15, quad = lane >> 4;
        const short8* bp = (const short8*)bop;
        for (int u = wave; u < 2 * KK2; u += 4) {
            const int kk = u >> 1, h = u & 1;         // k-chunk kc = 2*kk+h covers ch 32h..32h+31
            const int ki = kk / 3, kj = kk - ki * 3;
            const int y = ho - 1 + ki;                // wave-uniform
            if ((unsigned)y < HH) {
                const int col = wo0 + m + kj - 1;
                const int ccl = min(max(col, 0), WW - 1);
                const bool ok = (unsigned)col < WW;
                uint4 v = *(const uint4*)(xbB + (y * 64 + ccl) * 128 + quad * 16 + h * 64);
                if (!ok) { v.x = 0u; v.y = 0u; v.z = 0u; v.w = 0u; }
                const int kc = 2 * kk + h;
                acc0 = __builtin_amdgcn_mfma_f32_16x16x32_bf16(as_short8(v), bp[kc * 64 + lane], acc0, 0, 0, 0);
                acc1 = __builtin_amdgcn_mfma_f32_16x16x32_bf16(as_short8(v), bp[(NKC + kc) * 64 + lane], acc1, 0, 0, 0);
            }
        }
        // store wave partials: pacc[4][16 px][20 ch] aliases smp
        float* pacc = (float*)&smp[0][0];
        const int n = lane & 15;
        #pragma unroll
        for (int r = 0; r < 4; ++r) {
            const int p = quad * 4 + r;               // D: col=ch, row=quad*4+r (pixel)
            pacc[(wave * 16 + p) * 20 + n] = acc0[r];
            if (n < 2) pacc[(wave * 16 + p) * 20 + 16 + n] = acc1[r];
        }
    }
    __syncthreads();

    // ---- phase 2: reduce partials (float2) + bias + fold -> metal (144 taps, 1 thread each) ----
    if (t < NP * KK2) {
        const float* pacc = (const float*)&smp[0][0];
        const int p = t / KK2, kk = t - p * KK2;
        const float2 bb = *(const float2*)&boff[2 * kk];
        float2 d = bb;
        #pragma unroll
        for (int wv = 0; wv < 4; ++wv) {
            const float2 pp = *(const float2*)&pacc[(wv * 16 + p) * 20 + 2 * kk];
            d.x += pp.x; d.y += pp.y;
        }
        const float dy = d.x, dx = d.y;
        const int wo = wo0 + p;
        const int ki = kk / 3, kj = kk - ki * 3;
        const float py = (float)(ho - 1 + ki) + dy;
        const float px = (float)(wo - 1 + kj) + dx;
        const float y0f = floorf(py), x0f = floorf(px);
        const int y0 = (int)y0f, x0 = (int)x0f;
        const float wy1 = py - y0f, wx1 = px - x0f;
        const float wy0 = 1.f - wy1, wx0 = 1.f - wx1;
        const int yb = min(max(y0, 0), HH - 2);
        const int zb = min(max(x0, 0), WW - 2);
        const float vy0 = ((unsigned)y0 < HH) ? wy0 : 0.f;
        const float vy1 = ((unsigned)(y0 + 1) < HH) ? wy1 : 0.f;
        const float vx0 = ((unsigned)x0 < WW) ? wx0 : 0.f;
        const float vx1 = ((unsigned)(x0 + 1) < WW) ? wx1 : 0.f;
        const float t0 = (y0 == yb ? vy0 : 0.f) + (y0 + 1 == yb ? vy1 : 0.f);
        const float t1 = (y0 == yb + 1 ? vy0 : 0.f) + (y0 + 1 == yb + 1 ? vy1 : 0.f);
        const float u0 = (x0 == zb ? vx0 : 0.f) + (x0 + 1 == zb ? vx1 : 0.f);
        const float u1 = (x0 == zb + 1 ? vx0 : 0.f) + (x0 + 1 == zb + 1 ? vx1 : 0.f);
        union { unsigned int u; _Float16 h[2]; } c0, c1;
        c0.h[0] = (_Float16)(t0 * u0); c0.h[1] = (_Float16)(t1 * u0);  // w00, w10 (col zb)
        c1.h[0] = (_Float16)(t0 * u1); c1.h[1] = (_Float16)(t1 * u1);  // w01, w11 (col zb+1)
        uint4 mt;
        mt.x = (unsigned int)((yb * 64 + zb) * 128);  // byte offset into bf16 image
        mt.y = c0.u; mt.z = c1.u; mt.w = 0u;
        metal[t] = mt;
    }
    __syncthreads();                                  // pacc reads done; metal ready

    // ---- phase 3: gather (4 px/wave, 2 taps/iter, 20 loads in flight) -> smp ----
    {
        const int li = lane & 31;                     // channel pair index
        const int h  = lane >> 5;                     // half -> tap select
        const char* xli = xbB + li * 4;
        #pragma unroll
        for (int q = 0; q < 4; ++q) {
            const int p = wave * 4 + q;
            uint4 mtj[5];
            #pragma unroll
            for (int j = 0; j < 5; ++j) {             // 5 ds_read_b128, 2-addr broadcast
                const int kk = min(2 * j + h, 8);
                mtj[j] = metal[p * KK2 + kk];
            }
            unsigned int rg[5][4];
            #pragma unroll
            for (int j = 0; j < 5; ++j) {             // 20 global loads issued together
                const char* base = xli + (int)mtj[j].x;
                rg[j][0] = *(const unsigned int*)(base);          // row yb,   col zb
                rg[j][1] = *(const unsigned int*)(base + 128);    // row yb,   col zb+1
                rg[j][2] = *(const unsigned int*)(base + 8192);   // row yb+1, col zb
                rg[j][3] = *(const unsigned int*)(base + 8320);   // row yb+1, col zb+1
            }
            #pragma unroll
            for (int j = 0; j < 5; ++j) {
                union { unsigned int u; _Float16 f[2]; } c0, c1;
                c0.u = mtj[j].y; c1.u = mtj[j].z;
                const float w00 = (float)c0.f[0], w10 = (float)c0.f[1];
                const float w01 = (float)c1.f[0], w11 = (float)c1.f[1];
                const float a0l = u2f(rg[j][0] << 16), a0h = u2f(rg[j][0] & 0xffff0000u);
                const float a1l = u2f(rg[j][1] << 16), a1h = u2f(rg[j][1] & 0xffff0000u);
                const float b0l = u2f(rg[j][2] << 16), b0h = u2f(rg[j][2] & 0xffff0000u);
                const float b1l = u2f(rg[j][3] << 16), b1h = u2f(rg[j][3] & 0xffff0000u);
                const float vl = w00 * a0l + w01 * a1l + w10 * b0l + w11 * b1l;
                const float vh = w00 * a0h + w01 * a1h + w10 * b0h + w11 * b1h;
                const int kk = min(2 * j + h, 8);     // j==4: both halves write same data
                __hip_bfloat162 pk;
                pk.x = __float2bfloat16(vl);
                pk.y = __float2bfloat16(vh);
                *(__hip_bfloat162*)((char*)&smp[p][0] + kk * 128 + li * 4) = pk;
            }
        }
    }
    __syncthreads();

    // ---- phase 4: main GEMM 16 x 576 @ 576 x 64; wave = 16-col N-tile ----
    f32x4 acc = {0.f, 0.f, 0.f, 0.f};
    {
        const char* abase = (const char*)&smp[lane & 15][0] + (lane >> 4) * 16;
        const short8* wp = (const short8*)wmp + wave * NKC * 64 + lane;
        #pragma unroll
        for (int kc = 0; kc < NKC; ++kc) {
            const short8 a  = *(const short8*)(abase + kc * 64);   // ds_read_b128
            const short8 bw = wp[kc * 64];                         // global, L1/L2-hot
            acc = __builtin_amdgcn_mfma_f32_16x16x32_bf16(a, bw, acc, 0, 0, 0);
        }
    }
    __syncthreads();                                  // smp reads done; alias as outb

    // ---- phase 5: epilogue via LDS for coalesced stores ----
    {
        float* outb = (float*)&smp[0][0];             // [64][17] floats = 4352 B
        const int o = wave * 16 + (lane & 15);
        const float bias = bconv[o];
        const int pr = (lane >> 4) * 4;
        #pragma unroll
        for (int r = 0; r < 4; ++r)
            outb[o * 17 + pr + r] = acc[r] + bias;
    }
    __syncthreads();
    {
        const float* outb = (const float*)&smp[0][0];
        const int oo = t >> 2, pxb = (t & 3) * 4;
        const float* lb = outb + oo * 17 + pxb;
        float4 v;
        v.x = lb[0]; v.y = lb[1]; v.z = lb[2]; v.w = lb[3];
        *(float4*)(out + ((size_t)(b * COUT + oo)) * HW + sp0 + pxb) = v;
    }
}

extern "C" void kernel_launch(void* const* d_in, const int* in_sizes, int n_in,
                              void* d_out, int out_size, void* d_ws, size_t ws_size,
                              hipStream_t stream) {
    const float* x      = (const float*)d_in[0];
    const float* w_off  = (const float*)d_in[1];
    const float* b_off  = (const float*)d_in[2];
    const float* w_conv = (const float*)d_in[3];
    const float* b_conv = (const float*)d_in[4];
    float* out = (float*)d_out;

    // ws: xT bf16 16.78MB | wmp 73728B | bop 36864B
    __hip_bfloat16* xT  = (__hip_bfloat16*)d_ws;
    __hip_bfloat16* wmp = xT + (size_t)32 * HW * CIN;
    __hip_bfloat16* bop = wmp + 4 * NKC * 64 * 8;

    hipLaunchKernelGGL(prep, dim3(2048 + 216), dim3(256), 0, stream,
                       x, w_conv, w_off, xT, wmp, bop);
    hipLaunchKernelGGL(deform_fused, dim3(32 * HW / NP), dim3(256), 0, stream,
                       xT, bop, wmp, b_off, b_conv, out);
}